// Round 4
// baseline (813.361 us; speedup 1.0000x reference)
//
#include <hip/hip_runtime.h>
#include <hip/hip_bf16.h>
#include <cstdint>
#include <cstddef>

using bf16 = __hip_bfloat16;
typedef __bf16 bf16x8 __attribute__((ext_vector_type(8)));
typedef float floatx4 __attribute__((ext_vector_type(4)));

#define B_  2
#define T_  4096
#define C_  2048
#define H_  16
#define HK_ 8
#define D_  128
#define W_  512
#define BT_ (B_*T_)

__device__ __forceinline__ floatx4 mfma16(bf16x8 a, bf16x8 b, floatx4 c) {
  return __builtin_amdgcn_mfma_f32_16x16x32_bf16(a, b, c, 0, 0, 0);
}
__device__ __forceinline__ __bf16 f2b(float f) {
  union { bf16 h; __bf16 b; } u; u.h = __float2bfloat16(f); return u.b;
}
// load 8 consecutive elements as bf16x8, converting if the source is f32
__device__ __forceinline__ bf16x8 load8(const bf16* p) {
  return *(const bf16x8*)(const void*)p;
}
__device__ __forceinline__ bf16x8 load8(const float* p) {
  float4 a = *(const float4*)(const void*)p;
  float4 b = *(const float4*)(const void*)(p + 4);
  bf16x8 r;
  r[0]=f2b(a.x); r[1]=f2b(a.y); r[2]=f2b(a.z); r[3]=f2b(a.w);
  r[4]=f2b(b.x); r[5]=f2b(b.y); r[6]=f2b(b.z); r[7]=f2b(b.w);
  return r;
}
__device__ __forceinline__ void store1(float* p, float v) { *p = v; }
__device__ __forceinline__ void store1(bf16*  p, float v) { *p = __float2bfloat16(v); }

// C[m][n] = sum_k A[m][k] * Bw[n][k].  M,N multiples of 128; Kd multiple of 64.
// A/B may be f32 (converted to bf16 during LDS staging) or bf16.
template<typename TA, typename TB, typename TC>
__global__ __launch_bounds__(256) void gemm_nt(const TA* __restrict__ A,
                                               const TB* __restrict__ Bw,
                                               TC* __restrict__ Cc,
                                               int M, int N, int Kd) {
  __shared__ alignas(16) bf16 As[128*64];
  __shared__ alignas(16) bf16 Bs[128*64];
  const int tid = threadIdx.x;
  const int w = tid >> 6, lane = tid & 63;
  const int quad = lane >> 4, l16 = lane & 15;
  const int wm = (w & 1) * 64, wn = (w >> 1) * 64;
  const int m0 = blockIdx.y * 128, n0 = blockIdx.x * 128;
  const int srow = lane >> 3, g = lane & 7;   // global 8-elem seg index 0..7

  floatx4 acc[4][4];
  #pragma unroll
  for (int i = 0; i < 4; ++i)
    #pragma unroll
    for (int j = 0; j < 4; ++j) acc[i][j] = (floatx4){0.f, 0.f, 0.f, 0.f};

  for (int k0 = 0; k0 < Kd; k0 += 64) {
    __syncthreads();
    #pragma unroll
    for (int i = 0; i < 4; ++i) {
      const int r = w*32 + i*8 + srow;        // tile row 0..127
      const int s = g ^ (r & 7);              // swizzled LDS seg
      bf16x8 va = load8(A  + (size_t)(m0 + r)*Kd + k0 + g*8);
      bf16x8 vb = load8(Bw + (size_t)(n0 + r)*Kd + k0 + g*8);
      *(bf16x8*)(void*)(As + r*64 + s*8) = va;
      *(bf16x8*)(void*)(Bs + r*64 + s*8) = vb;
    }
    __syncthreads();
    #pragma unroll
    for (int kk = 0; kk < 2; ++kk) {
      bf16x8 af[4], bfr[4];
      #pragma unroll
      for (int mt = 0; mt < 4; ++mt) {
        const int m = wm + mt*16 + l16;
        af[mt] = load8(As + m*64 + (((kk*4 + quad) ^ (m & 7)) * 8));
      }
      #pragma unroll
      for (int nt = 0; nt < 4; ++nt) {
        const int n = wn + nt*16 + l16;
        bfr[nt] = load8(Bs + n*64 + (((kk*4 + quad) ^ (n & 7)) * 8));
      }
      #pragma unroll
      for (int mt = 0; mt < 4; ++mt)
        #pragma unroll
        for (int nt = 0; nt < 4; ++nt)
          acc[mt][nt] = mfma16(af[mt], bfr[nt], acc[mt][nt]);
    }
  }

  #pragma unroll
  for (int mt = 0; mt < 4; ++mt)
    #pragma unroll
    for (int r = 0; r < 4; ++r) {
      const size_t row = (size_t)(m0 + wm + mt*16 + quad*4 + r);
      #pragma unroll
      for (int nt = 0; nt < 4; ++nt) {
        const int col = n0 + wn + nt*16 + l16;
        store1(Cc + row*N + col, acc[mt][nt][r]);
      }
    }
}

// grid (BT, 32), block 128.
// j in [0,16): rope+rms on Q head j (in-place, bf16)
// j in [16,24): rope+rms on K head j-16 (in-place, bf16)
// j in [24,32): V[hk] += gate*ve (in-place, bf16; x/ve/wgate are f32)
__global__ __launch_bounds__(128) void fuse_k(const float* __restrict__ x,
                                              const float* __restrict__ ve,
                                              const float* __restrict__ cosb,
                                              const float* __restrict__ sinb,
                                              const float* __restrict__ wgate,
                                              bf16* __restrict__ Q,
                                              bf16* __restrict__ Kw,
                                              bf16* __restrict__ Vw) {
  const int tok = blockIdx.x;
  const int j   = blockIdx.y;
  const int t   = tok & (T_ - 1);
  const int tid = threadIdx.x;

  if (j < 24) {
    bf16* base = (j < 16) ? (Q + (size_t)tok * C_ + j * D_)
                          : (Kw + (size_t)tok * (HK_*D_) + (j - 16) * D_);
    const int d  = tid;
    const float v0 = __bfloat162float(base[d]);
    const float vp = __bfloat162float(base[d ^ 64]);
    const int dd = d & 63;
    const float c = cosb[t*64 + dd];
    const float s = sinb[t*64 + dd];
    // d<64: x1*c + x2*s ; d>=64: -x1*s + x2*c  (x1=base[d&63], x2=base[(d&63)+64])
    const float val = (d < 64) ? (v0*c + vp*s) : (v0*c - vp*s);
    float ss = val * val;
    #pragma unroll
    for (int off = 1; off < 64; off <<= 1) ss += __shfl_xor(ss, off);
    __shared__ float red[2];
    if ((tid & 63) == 0) red[tid >> 6] = ss;
    __syncthreads();
    const float tot = red[0] + red[1];
    const float sc = rsqrtf(tot * (1.0f/128.0f) + 1.1920929e-7f);
    base[d] = __float2bfloat16(val * sc);
  } else {
    const int hk = j - 24;
    float z = 0.f;
    #pragma unroll
    for (int c = 0; c < 32; ++c)
      z += x[(size_t)tok * C_ + c] * wgate[hk*32 + c];
    const float gate = 2.0f / (1.0f + __expf(-z));
    const size_t idx = (size_t)tok * (HK_*D_) + hk * D_ + tid;
    Vw[idx] = __float2bfloat16(__bfloat162float(Vw[idx]) + gate * ve[idx]);
  }
}

// Flash-style windowed attention. grid (T/128, H, B), block 256 (4 waves).
// wave w handles queries q0..q0+31 (2 m-tiles of 16).
// NOTE: Y may alias Q (in-place): each block's (row, head-col) output range is
// read as Q only by that same block, and all Q reads precede all Y writes.
__global__ __launch_bounds__(256) void attn_k(const bf16* Q,
                                              const bf16* __restrict__ K,
                                              const bf16* __restrict__ V,
                                              bf16* Y) {
  const int t0 = blockIdx.x * 128;
  const int h  = blockIdx.y, bb = blockIdx.z, hk = h >> 1;
  const int tid = threadIdx.x, w = tid >> 6, lane = tid & 63;
  const int quad = lane >> 4, l16 = lane & 15;
  const int q0 = t0 + w * 32;
  const float scale = 0.08838834764831845f;  // 1/sqrt(128)

  __shared__ alignas(16) bf16 Ks[32*128];
  __shared__ alignas(16) bf16 Vt[128*40];
  __shared__ alignas(16) bf16 Ps[4][32*40];

  // Q fragments (A-layout): qf[mt][kc][j] = Q[q0+mt*16+l16][kc*32+quad*8+j]
  bf16x8 qf[2][4];
  #pragma unroll
  for (int mt = 0; mt < 2; ++mt)
    #pragma unroll
    for (int kc = 0; kc < 4; ++kc)
      qf[mt][kc] = load8(Q + (size_t)(bb*T_ + q0 + mt*16 + l16)*C_ + h*D_ + kc*32 + quad*8);

  floatx4 o[2][8];
  #pragma unroll
  for (int mt = 0; mt < 2; ++mt)
    #pragma unroll
    for (int nt = 0; nt < 8; ++nt) o[mt][nt] = (floatx4){0.f, 0.f, 0.f, 0.f};
  float mr[2][4], lr[2][4];
  #pragma unroll
  for (int mt = 0; mt < 2; ++mt)
    #pragma unroll
    for (int r = 0; r < 4; ++r) { mr[mt][r] = -1.0e30f; lr[mt][r] = 0.f; }

  const int kb0 = (t0 >= W_) ? (t0 - W_) : 0;
  for (int kb = kb0; kb < t0 + 128; kb += 32) {
    __syncthreads();
    // stage K chunk (32 keys x 128 d), xor-swizzled; coalesced 16B loads
    #pragma unroll
    for (int jj = 0; jj < 2; ++jj) {
      const int id  = jj*256 + tid;            // 0..511
      const int row = id >> 4;                 // key row 0..31
      const int gg  = id & 15;                 // global 16B seg 0..15
      const int s   = gg ^ (row & 7);          // swizzled LDS seg (low 3 bits)
      bf16x8 vk = load8(K + (size_t)(bb*T_ + kb + row)*(HK_*D_) + hk*D_ + gg*8);
      *(bf16x8*)(void*)(Ks + row*128 + ((gg & 8) | (s & 7))*8) = vk;
    }
    // stage V chunk transposed: Vt[d][key] with key-block swizzle
    #pragma unroll
    for (int jj = 0; jj < 2; ++jj) {
      const int idx = jj*256 + tid;            // 0..511
      const int key = idx >> 4, seg = idx & 15;
      union { bf16x8 v; bf16 hv[8]; } tmp;
      tmp.v = load8(V + (size_t)(bb*T_ + kb + key)*(HK_*D_) + hk*D_ + seg*8);
      const int col = (((key >> 3) ^ (seg & 3)) * 8) + (key & 7);
      #pragma unroll
      for (int e = 0; e < 8; ++e)
        Vt[(seg*8 + e)*40 + col] = tmp.hv[e];
    }
    __syncthreads();

    // S = Q K^T  (two 16-key n-tiles)
    floatx4 s[2][2];
    s[0][0] = (floatx4){0.f,0.f,0.f,0.f}; s[0][1] = (floatx4){0.f,0.f,0.f,0.f};
    s[1][0] = (floatx4){0.f,0.f,0.f,0.f}; s[1][1] = (floatx4){0.f,0.f,0.f,0.f};
    #pragma unroll
    for (int kc = 0; kc < 4; ++kc) {
      const int c8 = kc*4 + quad;              // global seg 0..15 (8-elem units)
      const int s0 = (c8 & 8) | ((c8 ^ (l16 & 7)) & 7);
      bf16x8 bk0 = load8(Ks + l16*128 + s0*8);
      bf16x8 bk1 = load8(Ks + (16 + l16)*128 + s0*8);
      s[0][0] = mfma16(qf[0][kc], bk0, s[0][0]);
      s[0][1] = mfma16(qf[0][kc], bk1, s[0][1]);
      s[1][0] = mfma16(qf[1][kc], bk0, s[1][0]);
      s[1][1] = mfma16(qf[1][kc], bk1, s[1][1]);
    }

    // online softmax update per row
    #pragma unroll
    for (int mt = 0; mt < 2; ++mt)
      #pragma unroll
      for (int r = 0; r < 4; ++r) {
        const int qg  = q0 + mt*16 + quad*4 + r;
        const int kg0 = kb + l16, kg1 = kb + 16 + l16;
        float sv0 = (kg0 <= qg && kg0 + W_ >= qg) ? s[mt][0][r] * scale : -3.0e38f;
        float sv1 = (kg1 <= qg && kg1 + W_ >= qg) ? s[mt][1][r] * scale : -3.0e38f;
        float mx = fmaxf(sv0, sv1);
        #pragma unroll
        for (int off = 1; off < 16; off <<= 1) mx = fmaxf(mx, __shfl_xor(mx, off));
        const float mnew  = fmaxf(mr[mt][r], mx);
        const float alpha = __expf(mr[mt][r] - mnew);
        mr[mt][r] = mnew;
        const float p0 = __expf(sv0 - mnew);
        const float p1 = __expf(sv1 - mnew);
        float ps = p0 + p1;
        #pragma unroll
        for (int off = 1; off < 16; off <<= 1) ps += __shfl_xor(ps, off);
        lr[mt][r] = lr[mt][r] * alpha + ps;
        const int prow = mt*16 + quad*4 + r;
        Ps[w][prow*40 + l16]      = __float2bfloat16(p0);
        Ps[w][prow*40 + 16 + l16] = __float2bfloat16(p1);
        #pragma unroll
        for (int nt = 0; nt < 8; ++nt) o[mt][nt][r] *= alpha;
      }

    // pin Ps store->load order across the type-punned LDS accesses
    __syncthreads();

    // P·V
    bf16x8 pa0 = load8(&Ps[w][l16*40 + quad*8]);
    bf16x8 pa1 = load8(&Ps[w][(16 + l16)*40 + quad*8]);
    #pragma unroll
    for (int nt = 0; nt < 8; ++nt) {
      const int d   = nt*16 + l16;
      const int blk = quad ^ ((d >> 3) & 3);
      bf16x8 bv = load8(Vt + d*40 + blk*8);
      o[0][nt] = mfma16(pa0, bv, o[0][nt]);
      o[1][nt] = mfma16(pa1, bv, o[1][nt]);
    }
  }

  // epilogue: O / l  (Y may alias Q; all Q reads already done)
  #pragma unroll
  for (int mt = 0; mt < 2; ++mt)
    #pragma unroll
    for (int r = 0; r < 4; ++r) {
      const float inv = 1.0f / lr[mt][r];
      const size_t rowoff = (size_t)(bb*T_ + q0 + mt*16 + quad*4 + r) * C_ + h*D_;
      #pragma unroll
      for (int nt = 0; nt < 8; ++nt)
        Y[rowoff + nt*16 + l16] = __float2bfloat16(o[mt][nt][r] * inv);
    }
}

extern "C" void kernel_launch(void* const* d_in, const int* in_sizes, int n_in,
                              void* d_out, int out_size, void* d_ws, size_t ws_size,
                              hipStream_t stream) {
  (void)in_sizes; (void)n_in; (void)out_size; (void)ws_size;
  // All inputs are float32 per the reference (prior rounds' bf16 cast was the
  // NaN source: f32 bits reinterpreted as bf16 contain NaN patterns).
  const float* x     = (const float*)d_in[0];
  const float* ve    = (const float*)d_in[1];
  const float* cosb  = (const float*)d_in[2];
  const float* sinb  = (const float*)d_in[3];
  const float* wq    = (const float*)d_in[4];
  const float* wk    = (const float*)d_in[5];
  const float* wv    = (const float*)d_in[6];
  const float* wproj = (const float*)d_in[7];
  const float* wgate = (const float*)d_in[8];
  // d_in[9] = window_size (always 512 for this problem)

  bf16* Q  = (bf16*)d_ws;                       // [BT, 2048]; attn writes Y in-place
  bf16* Kw = Q  + (size_t)BT_ * C_;             // [BT, 1024]
  bf16* Vw = Kw + (size_t)BT_ * (HK_*D_);       // [BT, 1024]   total ws = 67.1 MB

  gemm_nt<float,float,bf16><<<dim3(C_/128,       BT_/128), 256, 0, stream>>>(x, wq, Q,  BT_, C_,     C_);
  gemm_nt<float,float,bf16><<<dim3((HK_*D_)/128, BT_/128), 256, 0, stream>>>(x, wk, Kw, BT_, HK_*D_, C_);
  gemm_nt<float,float,bf16><<<dim3((HK_*D_)/128, BT_/128), 256, 0, stream>>>(x, wv, Vw, BT_, HK_*D_, C_);
  fuse_k<<<dim3(BT_, 32), 128, 0, stream>>>(x, ve, cosb, sinb, wgate, Q, Kw, Vw);
  attn_k<<<dim3(T_/128, H_, B_), 256, 0, stream>>>(Q, Kw, Vw, Q /*Y in-place*/);
  gemm_nt<bf16,float,float><<<dim3(C_/128, BT_/128), 256, 0, stream>>>(Q, wproj, (float*)d_out, BT_, C_, C_);
}

// Round 5
// 685.214 us; speedup vs baseline: 1.1870x; 1.1870x over previous
//
#include <hip/hip_runtime.h>
#include <hip/hip_bf16.h>
#include <cstdint>
#include <cstddef>

using bf16 = __hip_bfloat16;
typedef __bf16 bf16x8 __attribute__((ext_vector_type(8)));
typedef float floatx4 __attribute__((ext_vector_type(4)));

#define B_  2
#define T_  4096
#define C_  2048
#define H_  16
#define HK_ 8
#define D_  128
#define W_  512
#define BT_ (B_*T_)

__device__ __forceinline__ void gload_lds16(const void* g, void* l) {
  __builtin_amdgcn_global_load_lds((const __attribute__((address_space(1))) void*)g,
                                   (__attribute__((address_space(3))) void*)l, 16, 0, 0);
}
__device__ __forceinline__ floatx4 mfma16(bf16x8 a, bf16x8 b, floatx4 c) {
  return __builtin_amdgcn_mfma_f32_16x16x32_bf16(a, b, c, 0, 0, 0);
}
__device__ __forceinline__ __bf16 f2b(float f) {
  union { bf16 h; __bf16 b; } u; u.h = __float2bfloat16(f); return u.b;
}
__device__ __forceinline__ bf16x8 load8(const bf16* p) {
  return *(const bf16x8*)(const void*)p;
}
__device__ __forceinline__ bf16x8 load8(const float* p) {
  float4 a = *(const float4*)(const void*)p;
  float4 b = *(const float4*)(const void*)(p + 4);
  bf16x8 r;
  r[0]=f2b(a.x); r[1]=f2b(a.y); r[2]=f2b(a.z); r[3]=f2b(a.w);
  r[4]=f2b(b.x); r[5]=f2b(b.y); r[6]=f2b(b.z); r[7]=f2b(b.w);
  return r;
}
__device__ __forceinline__ void store1(float* p, float v) { *p = v; }
__device__ __forceinline__ void store1(bf16*  p, float v) { *p = __float2bfloat16(v); }

// One-shot f32 -> bf16 conversion of x and the four weight matrices.
// Block-uniform range selection; 2048 elems per 256-thread block.
__global__ __launch_bounds__(256) void cvt_k(const float* __restrict__ x,
                                             const float* __restrict__ wq,
                                             const float* __restrict__ wk,
                                             const float* __restrict__ wv,
                                             const float* __restrict__ wproj,
                                             bf16* __restrict__ xb,
                                             bf16* __restrict__ wqb,
                                             bf16* __restrict__ wkb,
                                             bf16* __restrict__ wvb,
                                             bf16* __restrict__ wprojb) {
  const int b = blockIdx.x;
  const float* src; bf16* dst; size_t off;
  if (b < 8192)       { src = x;     dst = xb;     off = (size_t)b * 2048; }          // 16.78M
  else if (b < 10240) { src = wq;    dst = wqb;    off = (size_t)(b-8192) * 2048; }   // 4.19M
  else if (b < 11264) { src = wk;    dst = wkb;    off = (size_t)(b-10240) * 2048; }  // 2.10M
  else if (b < 12288) { src = wv;    dst = wvb;    off = (size_t)(b-11264) * 2048; }  // 2.10M
  else                { src = wproj; dst = wprojb; off = (size_t)(b-12288) * 2048; }  // 4.19M
  const size_t i = off + (size_t)threadIdx.x * 8;
  *(bf16x8*)(void*)(dst + i) = load8(src + i);
}

// C[m][n] = sum_k A[m][k] * B[n][k], all-bf16 inputs, m97-style DMA staging.
// M,N multiples of 128; Kd multiple of 64.
template<typename TC>
__global__ __launch_bounds__(256) void gemm_bt(const bf16* __restrict__ A,
                                               const bf16* __restrict__ Bw,
                                               TC* __restrict__ Cc,
                                               int M, int N, int Kd) {
  __shared__ alignas(16) bf16 As[128*64];
  __shared__ alignas(16) bf16 Bs[128*64];
  const int tid = threadIdx.x;
  const int w = tid >> 6, lane = tid & 63;
  const int quad = lane >> 4, l16 = lane & 15;
  const int wm = (w & 1) * 64, wn = (w >> 1) * 64;
  const int m0 = blockIdx.y * 128, n0 = blockIdx.x * 128;
  const int srow = lane >> 3, sseg = lane & 7;

  floatx4 acc[4][4];
  #pragma unroll
  for (int i = 0; i < 4; ++i)
    #pragma unroll
    for (int j = 0; j < 4; ++j) acc[i][j] = (floatx4){0.f, 0.f, 0.f, 0.f};

  for (int k0 = 0; k0 < Kd; k0 += 64) {
    __syncthreads();
    #pragma unroll
    for (int i = 0; i < 4; ++i) {
      const int r  = w*32 + i*8 + srow;           // tile row this lane fetches
      const int gs = (sseg ^ (r & 7)) * 8;        // xor-swizzled global 16B seg
      // DMA: LDS dst is wave-uniform base + lane*16B -> LDS (row, seg lane&7)
      // holds global (row, seg (lane&7)^(row&7)).
      gload_lds16(A  + (size_t)(m0 + r)*Kd + k0 + gs, As + (w*32 + i*8)*64);
      gload_lds16(Bw + (size_t)(n0 + r)*Kd + k0 + gs, Bs + (w*32 + i*8)*64);
    }
    __syncthreads();
    #pragma unroll
    for (int kk = 0; kk < 2; ++kk) {
      bf16x8 af[4], bfr[4];
      #pragma unroll
      for (int mt = 0; mt < 4; ++mt) {
        const int m = wm + mt*16 + l16;
        af[mt] = load8(As + m*64 + (((kk*4 + quad) ^ (m & 7)) * 8));
      }
      #pragma unroll
      for (int nt = 0; nt < 4; ++nt) {
        const int n = wn + nt*16 + l16;
        bfr[nt] = load8(Bs + n*64 + (((kk*4 + quad) ^ (n & 7)) * 8));
      }
      #pragma unroll
      for (int mt = 0; mt < 4; ++mt)
        #pragma unroll
        for (int nt = 0; nt < 4; ++nt)
          acc[mt][nt] = mfma16(af[mt], bfr[nt], acc[mt][nt]);
    }
  }

  #pragma unroll
  for (int mt = 0; mt < 4; ++mt)
    #pragma unroll
    for (int r = 0; r < 4; ++r) {
      const size_t row = (size_t)(m0 + wm + mt*16 + quad*4 + r);
      #pragma unroll
      for (int nt = 0; nt < 4; ++nt) {
        const int col = n0 + wn + nt*16 + l16;
        store1(Cc + row*N + col, acc[mt][nt][r]);
      }
    }
}

// grid (BT, 32), block 128.
// j in [0,16): rope+rms on Q head j (in-place, bf16)
// j in [16,24): rope+rms on K head j-16 (in-place, bf16)
// j in [24,32): V[hk] += gate*ve (in-place, bf16; x/ve/wgate are f32)
__global__ __launch_bounds__(128) void fuse_k(const float* __restrict__ x,
                                              const float* __restrict__ ve,
                                              const float* __restrict__ cosb,
                                              const float* __restrict__ sinb,
                                              const float* __restrict__ wgate,
                                              bf16* __restrict__ Q,
                                              bf16* __restrict__ Kw,
                                              bf16* __restrict__ Vw) {
  const int tok = blockIdx.x;
  const int j   = blockIdx.y;
  const int t   = tok & (T_ - 1);
  const int tid = threadIdx.x;

  if (j < 24) {
    bf16* base = (j < 16) ? (Q + (size_t)tok * C_ + j * D_)
                          : (Kw + (size_t)tok * (HK_*D_) + (j - 16) * D_);
    const int d  = tid;
    const float v0 = __bfloat162float(base[d]);
    const float vp = __bfloat162float(base[d ^ 64]);
    const int dd = d & 63;
    const float c = cosb[t*64 + dd];
    const float s = sinb[t*64 + dd];
    const float val = (d < 64) ? (v0*c + vp*s) : (v0*c - vp*s);
    float ss = val * val;
    #pragma unroll
    for (int off = 1; off < 64; off <<= 1) ss += __shfl_xor(ss, off);
    __shared__ float red[2];
    if ((tid & 63) == 0) red[tid >> 6] = ss;
    __syncthreads();
    const float tot = red[0] + red[1];
    const float sc = rsqrtf(tot * (1.0f/128.0f) + 1.1920929e-7f);
    base[d] = __float2bfloat16(val * sc);
  } else {
    const int hk = j - 24;
    float z = 0.f;
    #pragma unroll
    for (int c = 0; c < 32; ++c)
      z += x[(size_t)tok * C_ + c] * wgate[hk*32 + c];
    const float gate = 2.0f / (1.0f + __expf(-z));
    const size_t idx = (size_t)tok * (HK_*D_) + hk * D_ + tid;
    Vw[idx] = __float2bfloat16(__bfloat162float(Vw[idx]) + gate * ve[idx]);
  }
}

// Flash-style windowed attention. grid (T/128, H, B), block 256 (4 waves).
// wave w handles queries q0..q0+31 (2 m-tiles of 16).
// Y aliases Q (in-place): each block's output range is read as Q only by that
// same block, and all Q reads precede all Y writes.
__global__ __launch_bounds__(256) void attn_k(const bf16* Q,
                                              const bf16* __restrict__ K,
                                              const bf16* __restrict__ V,
                                              bf16* Y) {
  const int t0 = blockIdx.x * 128;
  const int h  = blockIdx.y, bb = blockIdx.z, hk = h >> 1;
  const int tid = threadIdx.x, w = tid >> 6, lane = tid & 63;
  const int quad = lane >> 4, l16 = lane & 15;
  const int q0 = t0 + w * 32;
  const float scale = 0.08838834764831845f;  // 1/sqrt(128)

  __shared__ alignas(16) bf16 Ks[32*128];
  __shared__ alignas(16) bf16 Vt[128*40];
  __shared__ alignas(16) bf16 Ps[4][32*40];

  bf16x8 qf[2][4];
  #pragma unroll
  for (int mt = 0; mt < 2; ++mt)
    #pragma unroll
    for (int kc = 0; kc < 4; ++kc)
      qf[mt][kc] = load8(Q + (size_t)(bb*T_ + q0 + mt*16 + l16)*C_ + h*D_ + kc*32 + quad*8);

  floatx4 o[2][8];
  #pragma unroll
  for (int mt = 0; mt < 2; ++mt)
    #pragma unroll
    for (int nt = 0; nt < 8; ++nt) o[mt][nt] = (floatx4){0.f, 0.f, 0.f, 0.f};
  float mr[2][4], lr[2][4];
  #pragma unroll
  for (int mt = 0; mt < 2; ++mt)
    #pragma unroll
    for (int r = 0; r < 4; ++r) { mr[mt][r] = -1.0e30f; lr[mt][r] = 0.f; }

  const int kb0 = (t0 >= W_) ? (t0 - W_) : 0;
  for (int kb = kb0; kb < t0 + 128; kb += 32) {
    __syncthreads();
    #pragma unroll
    for (int jj = 0; jj < 2; ++jj) {
      const int id  = jj*256 + tid;            // 0..511
      const int row = id >> 4;                 // key row 0..31
      const int gg  = id & 15;                 // global 16B seg 0..15
      const int s   = gg ^ (row & 7);          // swizzled low 3 bits
      bf16x8 vk = load8(K + (size_t)(bb*T_ + kb + row)*(HK_*D_) + hk*D_ + gg*8);
      *(bf16x8*)(void*)(Ks + row*128 + ((gg & 8) | (s & 7))*8) = vk;
    }
    #pragma unroll
    for (int jj = 0; jj < 2; ++jj) {
      const int idx = jj*256 + tid;            // 0..511
      const int key = idx >> 4, seg = idx & 15;
      union { bf16x8 v; bf16 hv[8]; } tmp;
      tmp.v = load8(V + (size_t)(bb*T_ + kb + key)*(HK_*D_) + hk*D_ + seg*8);
      const int col = (((key >> 3) ^ (seg & 3)) * 8) + (key & 7);
      #pragma unroll
      for (int e = 0; e < 8; ++e)
        Vt[(seg*8 + e)*40 + col] = tmp.hv[e];
    }
    __syncthreads();

    floatx4 s[2][2];
    s[0][0] = (floatx4){0.f,0.f,0.f,0.f}; s[0][1] = (floatx4){0.f,0.f,0.f,0.f};
    s[1][0] = (floatx4){0.f,0.f,0.f,0.f}; s[1][1] = (floatx4){0.f,0.f,0.f,0.f};
    #pragma unroll
    for (int kc = 0; kc < 4; ++kc) {
      const int c8 = kc*4 + quad;
      const int s0 = (c8 & 8) | ((c8 ^ (l16 & 7)) & 7);
      bf16x8 bk0 = load8(Ks + l16*128 + s0*8);
      bf16x8 bk1 = load8(Ks + (16 + l16)*128 + s0*8);
      s[0][0] = mfma16(qf[0][kc], bk0, s[0][0]);
      s[0][1] = mfma16(qf[0][kc], bk1, s[0][1]);
      s[1][0] = mfma16(qf[1][kc], bk0, s[1][0]);
      s[1][1] = mfma16(qf[1][kc], bk1, s[1][1]);
    }

    #pragma unroll
    for (int mt = 0; mt < 2; ++mt)
      #pragma unroll
      for (int r = 0; r < 4; ++r) {
        const int qg  = q0 + mt*16 + quad*4 + r;
        const int kg0 = kb + l16, kg1 = kb + 16 + l16;
        float sv0 = (kg0 <= qg && kg0 + W_ >= qg) ? s[mt][0][r] * scale : -3.0e38f;
        float sv1 = (kg1 <= qg && kg1 + W_ >= qg) ? s[mt][1][r] * scale : -3.0e38f;
        float mx = fmaxf(sv0, sv1);
        #pragma unroll
        for (int off = 1; off < 16; off <<= 1) mx = fmaxf(mx, __shfl_xor(mx, off));
        const float mnew  = fmaxf(mr[mt][r], mx);
        const float alpha = __expf(mr[mt][r] - mnew);
        mr[mt][r] = mnew;
        const float p0 = __expf(sv0 - mnew);
        const float p1 = __expf(sv1 - mnew);
        float ps = p0 + p1;
        #pragma unroll
        for (int off = 1; off < 16; off <<= 1) ps += __shfl_xor(ps, off);
        lr[mt][r] = lr[mt][r] * alpha + ps;
        const int prow = mt*16 + quad*4 + r;
        Ps[w][prow*40 + l16]      = __float2bfloat16(p0);
        Ps[w][prow*40 + 16 + l16] = __float2bfloat16(p1);
        #pragma unroll
        for (int nt = 0; nt < 8; ++nt) o[mt][nt][r] *= alpha;
      }

    __syncthreads();

    bf16x8 pa0 = load8(&Ps[w][l16*40 + quad*8]);
    bf16x8 pa1 = load8(&Ps[w][(16 + l16)*40 + quad*8]);
    #pragma unroll
    for (int nt = 0; nt < 8; ++nt) {
      const int d   = nt*16 + l16;
      const int blk = quad ^ ((d >> 3) & 3);
      bf16x8 bv = load8(Vt + d*40 + blk*8);
      o[0][nt] = mfma16(pa0, bv, o[0][nt]);
      o[1][nt] = mfma16(pa1, bv, o[1][nt]);
    }
  }

  #pragma unroll
  for (int mt = 0; mt < 2; ++mt)
    #pragma unroll
    for (int r = 0; r < 4; ++r) {
      const float inv = 1.0f / lr[mt][r];
      const size_t rowoff = (size_t)(bb*T_ + q0 + mt*16 + quad*4 + r) * C_ + h*D_;
      #pragma unroll
      for (int nt = 0; nt < 8; ++nt)
        Y[rowoff + nt*16 + l16] = __float2bfloat16(o[mt][nt][r] * inv);
    }
}

extern "C" void kernel_launch(void* const* d_in, const int* in_sizes, int n_in,
                              void* d_out, int out_size, void* d_ws, size_t ws_size,
                              hipStream_t stream) {
  (void)in_sizes; (void)n_in; (void)out_size; (void)ws_size;
  const float* x     = (const float*)d_in[0];
  const float* ve    = (const float*)d_in[1];
  const float* cosb  = (const float*)d_in[2];
  const float* sinb  = (const float*)d_in[3];
  const float* wq    = (const float*)d_in[4];
  const float* wk    = (const float*)d_in[5];
  const float* wv    = (const float*)d_in[6];
  const float* wproj = (const float*)d_in[7];
  const float* wgate = (const float*)d_in[8];

  // ws layout (75.5 MB): Q | Kw | Vw | wprojb
  bf16* Q      = (bf16*)d_ws;                   // [BT, 2048]; attn writes Y in-place
  bf16* Kw     = Q  + (size_t)BT_ * C_;         // [BT, 1024]
  bf16* Vw     = Kw + (size_t)BT_ * (HK_*D_);   // [BT, 1024]
  bf16* wprojb = Vw + (size_t)BT_ * (HK_*D_);   // [2048, 2048]

  // Transient bf16 copies live INSIDE d_out (f32, 67.1 MB): they are dead
  // before the final GEMM overwrites d_out.
  bf16* xb  = (bf16*)d_out;                     // [BT, 2048]  33.55 MB
  bf16* wqb = xb  + (size_t)BT_ * C_;           // [2048, 2048] 8.39 MB
  bf16* wkb = wqb + (size_t)C_ * C_;            // [1024, 2048] 4.19 MB
  bf16* wvb = wkb + (size_t)(HK_*D_) * C_;      // [1024, 2048] 4.19 MB

  cvt_k<<<14336, 256, 0, stream>>>(x, wq, wk, wv, wproj, xb, wqb, wkb, wvb, wprojb);
  gemm_bt<bf16><<<dim3(C_/128,       BT_/128), 256, 0, stream>>>(xb, wqb, Q,  BT_, C_,     C_);
  gemm_bt<bf16><<<dim3((HK_*D_)/128, BT_/128), 256, 0, stream>>>(xb, wkb, Kw, BT_, HK_*D_, C_);
  gemm_bt<bf16><<<dim3((HK_*D_)/128, BT_/128), 256, 0, stream>>>(xb, wvb, Vw, BT_, HK_*D_, C_);
  fuse_k<<<dim3(BT_, 32), 128, 0, stream>>>(x, ve, cosb, sinb, wgate, Q, Kw, Vw);
  attn_k<<<dim3(T_/128, H_, B_), 256, 0, stream>>>(Q, Kw, Vw, Q /*Y in-place*/);
  gemm_bt<float><<<dim3(C_/128, BT_/128), 256, 0, stream>>>(Q, wprojb, (float*)d_out, BT_, C_, C_);
}